// Round 2
// baseline (396.413 us; speedup 1.0000x reference)
//
#include <hip/hip_runtime.h>
#include <hip/hip_bf16.h>

typedef __attribute__((ext_vector_type(8))) short short8;
typedef __attribute__((ext_vector_type(4))) float floatx4;

#define NRES 700
#define BATCH 128
#define DDIM 1024
#define HID 1024
// M = NRES*BATCH = 89600, K = 1024, N = 1024

__device__ __forceinline__ unsigned short f2bf(float f) {
  unsigned u = __float_as_uint(f);
  u = (u + 0x7FFFu + ((u >> 16) & 1u)) >> 16;  // round-to-nearest-even
  return (unsigned short)u;
}

// W1 [d][h] fp32 -> W1T [h][d] bf16 (so B-fragment reads are the verified B^T pattern)
__global__ void transpose_w1_kernel(const float* __restrict__ W1,
                                    unsigned short* __restrict__ W1T) {
  __shared__ float tile[32][33];
  int bx = blockIdx.x, by = blockIdx.y;
  int tx = threadIdx.x, ty = threadIdx.y;
#pragma unroll
  for (int i = 0; i < 32; i += 8)
    tile[ty + i][tx] = W1[(size_t)(by * 32 + ty + i) * HID + bx * 32 + tx];
  __syncthreads();
#pragma unroll
  for (int i = 0; i < 32; i += 8)
    W1T[(size_t)(bx * 32 + ty + i) * DDIM + by * 32 + tx] = f2bf(tile[tx][ty + i]);
}

__global__ void init_out_kernel(float* __restrict__ out, const float* __restrict__ b2, int n) {
  int i = blockIdx.x * blockDim.x + threadIdx.x;
  if (i < n) out[i] = b2[0];
}

// Fused: h = relu(A@W1 + b1); y = h@W2 (atomic accumulate, b2 pre-initialized).
// 128x128 tile, BK=64, 4 waves (2x2), 16x16x32 bf16 MFMA.
__launch_bounds__(256, 2)
__global__ void fused_mlp_kernel(const float* __restrict__ A,
                                 const unsigned short* __restrict__ W1T,
                                 const float* __restrict__ b1,
                                 const float* __restrict__ W2,
                                 float* __restrict__ out) {
  __shared__ unsigned short As[128 * 64];  // [row][k] bf16, 128B rows, XOR-swizzled
  __shared__ unsigned short Bs[128 * 64];  // [n][k] bf16 (from W1T), same swizzle

  int bid = blockIdx.x;
  // bijective XCD swizzle: 5600 = 8 XCDs * 700; each XCD walks n=0..7 fast, m slow
  int w = (bid & 7) * 700 + (bid >> 3);
  int blk_m = w >> 3;   // 0..699  (residue r)
  int blk_n = w & 7;    // 0..7
  int m0 = blk_m * 128;
  int n0 = blk_n * 128;

  int t = threadIdx.x;
  int lane = t & 63;
  int wid = t >> 6;
  int wm = wid >> 1, wn = wid & 1;       // 2x2 wave grid, each wave 64x64
  int lrow = lane & 15, lk = lane >> 4;  // fragment lane decomposition

  floatx4 acc[4][4];
#pragma unroll
  for (int i = 0; i < 4; ++i)
#pragma unroll
    for (int j = 0; j < 4; ++j)
      acc[i][j] = (floatx4)(0.f);

  for (int kt = 0; kt < 16; ++kt) {
    int k0 = kt * 64;
    // ---- stage A (fp32 -> bf16) and B (bf16) into swizzled LDS ----
#pragma unroll
    for (int i = 0; i < 4; ++i) {
      int c = i * 256 + t;           // chunk 0..1023, 8 elems each
      int row = c >> 3, c8 = c & 7;  // row 0..127, 16B chunk 0..7
      int dst = row * 64 + ((c8 ^ (row & 7)) * 8);  // ushort units, byte ^= (row&7)<<4

      const float* gp = A + (size_t)(m0 + row) * DDIM + k0 + c8 * 8;
      float4 f0 = *(const float4*)gp;
      float4 f1 = *(const float4*)(gp + 4);
      int4 pk;
      pk.x = f2bf(f0.x) | ((unsigned)f2bf(f0.y) << 16);
      pk.y = f2bf(f0.z) | ((unsigned)f2bf(f0.w) << 16);
      pk.z = f2bf(f1.x) | ((unsigned)f2bf(f1.y) << 16);
      pk.w = f2bf(f1.z) | ((unsigned)f2bf(f1.w) << 16);
      *(int4*)(&As[dst]) = pk;

      const unsigned short* gb = W1T + (size_t)(n0 + row) * DDIM + k0 + c8 * 8;
      *(int4*)(&Bs[dst]) = *(const int4*)gb;
    }
    __syncthreads();

    // ---- compute: 2 k-slices of 32, 16 MFMA each ----
#pragma unroll
    for (int ks = 0; ks < 2; ++ks) {
      short8 af[4], bf[4];
#pragma unroll
      for (int f = 0; f < 4; ++f) {
        int arow = wm * 64 + f * 16 + lrow;
        int ac = (ks * 4 + lk) ^ (arow & 7);
        af[f] = *(const short8*)(&As[arow * 64 + ac * 8]);
        int brow = wn * 64 + f * 16 + lrow;
        int bc = (ks * 4 + lk) ^ (brow & 7);
        bf[f] = *(const short8*)(&Bs[brow * 64 + bc * 8]);
      }
#pragma unroll
      for (int fm = 0; fm < 4; ++fm)
#pragma unroll
        for (int fn = 0; fn < 4; ++fn)
          acc[fm][fn] = __builtin_amdgcn_mfma_f32_16x16x32_bf16(af[fm], bf[fn], acc[fm][fn], 0, 0, 0);
    }
    __syncthreads();
  }

  // ---- epilogue: +b1, relu, dot with W2 (fp32), reduce 16 cols, atomicAdd ----
  float w2v[4], b1v[4];
#pragma unroll
  for (int fn = 0; fn < 4; ++fn) {
    int col = n0 + wn * 64 + fn * 16 + lrow;
    w2v[fn] = W2[col];
    b1v[fn] = b1[col];
  }
#pragma unroll
  for (int fm = 0; fm < 4; ++fm) {
#pragma unroll
    for (int j = 0; j < 4; ++j) {
      float p = 0.f;
#pragma unroll
      for (int fn = 0; fn < 4; ++fn) {
        float h = acc[fm][fn][j] + b1v[fn];
        h = fmaxf(h, 0.f);
        p += h * w2v[fn];
      }
      p += __shfl_xor(p, 1);
      p += __shfl_xor(p, 2);
      p += __shfl_xor(p, 4);
      p += __shfl_xor(p, 8);
      if ((lane & 15) == 0) {
        int row = wm * 64 + fm * 16 + (lk << 2) + j;  // local row = batch b
        atomicAdd(&out[row * NRES + blk_m], p);       // out[b*700 + r]
      }
    }
  }
}

extern "C" void kernel_launch(void* const* d_in, const int* in_sizes, int n_in,
                              void* d_out, int out_size, void* d_ws, size_t ws_size,
                              hipStream_t stream) {
  const float* s_s = (const float*)d_in[0];  // [700,128,1024] fp32
  const float* W1 = (const float*)d_in[1];   // [1024,1024]
  const float* b1 = (const float*)d_in[2];   // [1024]
  const float* W2 = (const float*)d_in[3];   // [1024,1]
  const float* b2 = (const float*)d_in[4];   // [1]
  float* out = (float*)d_out;                // [128,700,1] fp32

  unsigned short* W1T = (unsigned short*)d_ws;  // 2 MB bf16

  dim3 tb(32, 8);
  dim3 tg(HID / 32, DDIM / 32);
  transpose_w1_kernel<<<tg, tb, 0, stream>>>(W1, W1T);

  init_out_kernel<<<(out_size + 255) / 256, 256, 0, stream>>>(out, b2, out_size);

  fused_mlp_kernel<<<NRES * 8, 256, 0, stream>>>(s_s, W1T, b1, W2, out);
}